// Round 10
// baseline (295.398 us; speedup 1.0000x reference)
//
#include <hip/hip_runtime.h>
#include <math.h>

// ---- problem constants ----
#define N_TOK  11253
#define M_ROWS 22506
#define MP     22528          // M padded to multiple of 128
// levels: (H,W)=(92,92),(46,46),(23,23),(12,12); starts 0,8464,10580,11109

typedef __attribute__((ext_vector_type(8))) short bf16x8;
typedef __attribute__((ext_vector_type(4))) float f32x4;
typedef __attribute__((ext_vector_type(2))) float f32x2;
typedef __attribute__((ext_vector_type(2))) unsigned int u32x2;
typedef unsigned short ushort_t;
typedef unsigned int   uint32;

__device__ __forceinline__ float4 ld4(const float* p) { return *reinterpret_cast<const float4*>(p); }
__device__ __forceinline__ ushort_t f2bf(float f) {          // round-to-nearest-even
    uint32 u = __float_as_uint(f);
    u += 0x7fffu + ((u >> 16) & 1u);
    return (ushort_t)(u >> 16);
}
__device__ __forceinline__ float bf2f(ushort_t h) { return __uint_as_float(((uint32)h) << 16); }
__device__ __forceinline__ void gl_lds16(const void* g, void* l) {
    __builtin_amdgcn_global_load_lds(
        (const __attribute__((address_space(1))) unsigned int*)g,
        (__attribute__((address_space(3))) unsigned int*)l, 16, 0, 0);
}

// =============== bf16 MFMA GEMM: C = A @ Bt^T + bias ===============
// Tile 128x128, BK=64, 256 thr = 4 waves. Grid: (Nout/128, MP/128), n-tile fastest
// so adjacent blocks share the A row-panel (same-XCD L2 reuse).
// LDS swizzle: elem (r,k) at byte r*128 + (k*2 ^ ((r&7)<<4)); gl_lds dest linear,
// per-lane global source inverse-swizzled (rule 21).
template<int K, int OUT_BF16, int RELU>
__global__ __launch_bounds__(256) void mgemm_k(const ushort_t* __restrict__ A,
                                               const ushort_t* __restrict__ Bt,
                                               const float* __restrict__ bias,
                                               float* __restrict__ Cf,
                                               ushort_t* __restrict__ Cb,
                                               int Nout)
{
    __shared__ ushort_t As[128 * 64];   // 16KB
    __shared__ ushort_t Bs[128 * 64];   // 16KB
    const int tid = threadIdx.x;
    const int w = tid >> 6, l = tid & 63;
    const int wr = w >> 1, wc = w & 1;
    const int m0 = blockIdx.y * 128, n0 = blockIdx.x * 128;

    f32x4 acc[4][4];
    #pragma unroll
    for (int m = 0; m < 4; ++m)
        #pragma unroll
        for (int n = 0; n < 4; ++n)
            acc[m][n] = (f32x4){0.f, 0.f, 0.f, 0.f};

    const int srl  = l >> 3;
    const int skof = ((l & 7) ^ srl) << 3;
    const ushort_t* Agl = A  + (size_t)(m0 + srl) * K + skof;
    const ushort_t* Bgl = Bt + (size_t)(n0 + srl) * K + skof;

    const int fr = l & 15, fh = l >> 4;
    const int swz = (fr & 7) << 3;

    for (int k0 = 0; k0 < K; k0 += 64) {
        __syncthreads();
        #pragma unroll
        for (int j = 0; j < 4; ++j) {
            const int c = w + j * 4;
            gl_lds16(Agl + (size_t)(c * 8) * K + k0, &As[c * 512]);
            gl_lds16(Bgl + (size_t)(c * 8) * K + k0, &Bs[c * 512]);
        }
        __syncthreads();
        #pragma unroll
        for (int ks = 0; ks < 2; ++ks) {
            const int kus = (ks * 32 + fh * 8) ^ swz;
            bf16x8 af[4], bfv[4];
            #pragma unroll
            for (int m = 0; m < 4; ++m)
                af[m] = *reinterpret_cast<const bf16x8*>(&As[(wr * 64 + m * 16 + fr) * 64 + kus]);
            #pragma unroll
            for (int n = 0; n < 4; ++n)
                bfv[n] = *reinterpret_cast<const bf16x8*>(&Bs[(wc * 64 + n * 16 + fr) * 64 + kus]);
            #pragma unroll
            for (int m = 0; m < 4; ++m)
                #pragma unroll
                for (int n = 0; n < 4; ++n)
                    acc[m][n] = __builtin_amdgcn_mfma_f32_16x16x32_bf16(af[m], bfv[n], acc[m][n], 0, 0, 0);
        }
    }

    const int col0 = n0 + wc * 64;
    #pragma unroll
    for (int n = 0; n < 4; ++n) {
        const int cg = col0 + n * 16 + fr;
        const float bv = bias[cg];
        #pragma unroll
        for (int m = 0; m < 4; ++m) {
            const int rg = m0 + wr * 64 + m * 16 + fh * 4;
            #pragma unroll
            for (int q = 0; q < 4; ++q) {
                float v = acc[m][n][q] + bv;
                if (RELU) v = fmaxf(v, 0.f);
                const size_t o = (size_t)(rg + q) * Nout + cg;
                if (OUT_BF16) Cb[o] = f2bf(v);
                else          Cf[o] = v;
            }
        }
    }
}

// =============== bf16 MFMA GEMM, 128x64 tile (for small-N latency-bound GEMMs) ===============
// Grid: (Nout/64, MP/128), n-tile fastest. 4 waves = 2 row-halves x 2 col-halves(32), acc[4][2].
template<int K, int OUT_BF16, int RELU>
__global__ __launch_bounds__(256) void mgemm64_k(const ushort_t* __restrict__ A,
                                                 const ushort_t* __restrict__ Bt,
                                                 const float* __restrict__ bias,
                                                 float* __restrict__ Cf,
                                                 ushort_t* __restrict__ Cb,
                                                 int Nout)
{
    __shared__ ushort_t As[128 * 64];   // 16KB
    __shared__ ushort_t Bs[64 * 64];    // 8KB
    const int tid = threadIdx.x;
    const int w = tid >> 6, l = tid & 63;
    const int wr = w >> 1, wc = w & 1;
    const int m0 = blockIdx.y * 128, n0 = blockIdx.x * 64;

    f32x4 acc[4][2];
    #pragma unroll
    for (int m = 0; m < 4; ++m)
        #pragma unroll
        for (int n = 0; n < 2; ++n)
            acc[m][n] = (f32x4){0.f, 0.f, 0.f, 0.f};

    const int srl  = l >> 3;
    const int skof = ((l & 7) ^ srl) << 3;
    const ushort_t* Agl = A  + (size_t)(m0 + srl) * K + skof;
    const ushort_t* Bgl = Bt + (size_t)(n0 + srl) * K + skof;

    const int fr = l & 15, fh = l >> 4;
    const int swz = (fr & 7) << 3;

    for (int k0 = 0; k0 < K; k0 += 64) {
        __syncthreads();
        // 24 chunks: 0-15 = A rows 8c..8c+8, 16-23 = B rows
        #pragma unroll
        for (int j = 0; j < 6; ++j) {
            const int c = w + j * 4;
            if (c < 16) gl_lds16(Agl + (size_t)(c * 8) * K + k0, &As[c * 512]);
            else        gl_lds16(Bgl + (size_t)((c - 16) * 8) * K + k0, &Bs[(c - 16) * 512]);
        }
        __syncthreads();
        #pragma unroll
        for (int ks = 0; ks < 2; ++ks) {
            const int kus = (ks * 32 + fh * 8) ^ swz;
            bf16x8 af[4], bfv[2];
            #pragma unroll
            for (int m = 0; m < 4; ++m)
                af[m] = *reinterpret_cast<const bf16x8*>(&As[(wr * 64 + m * 16 + fr) * 64 + kus]);
            #pragma unroll
            for (int n = 0; n < 2; ++n)
                bfv[n] = *reinterpret_cast<const bf16x8*>(&Bs[(wc * 32 + n * 16 + fr) * 64 + kus]);
            #pragma unroll
            for (int m = 0; m < 4; ++m)
                #pragma unroll
                for (int n = 0; n < 2; ++n)
                    acc[m][n] = __builtin_amdgcn_mfma_f32_16x16x32_bf16(af[m], bfv[n], acc[m][n], 0, 0, 0);
        }
    }

    const int col0 = n0 + wc * 32;
    #pragma unroll
    for (int n = 0; n < 2; ++n) {
        const int cg = col0 + n * 16 + fr;
        const float bv = bias[cg];
        #pragma unroll
        for (int m = 0; m < 4; ++m) {
            const int rg = m0 + wr * 64 + m * 16 + fh * 4;
            #pragma unroll
            for (int q = 0; q < 4; ++q) {
                float v = acc[m][n][q] + bv;
                if (RELU) v = fmaxf(v, 0.f);
                const size_t o = (size_t)(rg + q) * Nout + cg;
                if (OUT_BF16) Cb[o] = f2bf(v);
                else          Cf[o] = v;
            }
        }
    }
}

// =============== merged front GEMM: [V | OA] = [qb|qpb] @ [Wv|Woa]^T ===============
// Grid: (5, MP/128), n-tile fastest. x 0-1: A=qb -> V bf16; x 2-4: A=qpb -> OA f32.
__global__ __launch_bounds__(256) void vgemm_k(const ushort_t* __restrict__ qb,
                                               const ushort_t* __restrict__ qpb,
                                               const ushort_t* __restrict__ Wcat,
                                               const float* __restrict__ b_value,
                                               const float* __restrict__ b_off,
                                               const float* __restrict__ b_attn,
                                               ushort_t* __restrict__ V,
                                               float* __restrict__ OA)
{
    const int K = 256;
    __shared__ ushort_t As[128 * 64];
    __shared__ ushort_t Bs[128 * 64];
    const int tid = threadIdx.x;
    const int w = tid >> 6, l = tid & 63;
    const int wr = w >> 1, wc = w & 1;
    const int by = blockIdx.x;
    const int m0 = blockIdx.y * 128, n0 = by * 128;
    const ushort_t* A = (by < 2) ? qb : qpb;

    f32x4 acc[4][4];
    #pragma unroll
    for (int m = 0; m < 4; ++m)
        #pragma unroll
        for (int n = 0; n < 4; ++n)
            acc[m][n] = (f32x4){0.f, 0.f, 0.f, 0.f};

    const int srl  = l >> 3;
    const int skof = ((l & 7) ^ srl) << 3;
    const ushort_t* Agl = A    + (size_t)(m0 + srl) * K + skof;
    const ushort_t* Bgl = Wcat + (size_t)(n0 + srl) * K + skof;

    const int fr = l & 15, fh = l >> 4;
    const int swz = (fr & 7) << 3;

    for (int k0 = 0; k0 < K; k0 += 64) {
        __syncthreads();
        #pragma unroll
        for (int j = 0; j < 4; ++j) {
            const int c = w + j * 4;
            gl_lds16(Agl + (size_t)(c * 8) * K + k0, &As[c * 512]);
            gl_lds16(Bgl + (size_t)(c * 8) * K + k0, &Bs[c * 512]);
        }
        __syncthreads();
        #pragma unroll
        for (int ks = 0; ks < 2; ++ks) {
            const int kus = (ks * 32 + fh * 8) ^ swz;
            bf16x8 af[4], bfv[4];
            #pragma unroll
            for (int m = 0; m < 4; ++m)
                af[m] = *reinterpret_cast<const bf16x8*>(&As[(wr * 64 + m * 16 + fr) * 64 + kus]);
            #pragma unroll
            for (int n = 0; n < 4; ++n)
                bfv[n] = *reinterpret_cast<const bf16x8*>(&Bs[(wc * 64 + n * 16 + fr) * 64 + kus]);
            #pragma unroll
            for (int m = 0; m < 4; ++m)
                #pragma unroll
                for (int n = 0; n < 4; ++n)
                    acc[m][n] = __builtin_amdgcn_mfma_f32_16x16x32_bf16(af[m], bfv[n], acc[m][n], 0, 0, 0);
        }
    }

    const int col0 = n0 + wc * 64;
    #pragma unroll
    for (int n = 0; n < 4; ++n) {
        const int cg = col0 + n * 16 + fr;
        float bv;
        if (by < 2)           bv = b_value[cg];
        else if (cg < 512)    bv = b_off[cg - 256];
        else                  bv = b_attn[cg - 512];
        #pragma unroll
        for (int m = 0; m < 4; ++m) {
            const int rg = m0 + wr * 64 + m * 16 + fh * 4;
            #pragma unroll
            for (int q = 0; q < 4; ++q) {
                const float v = acc[m][n][q] + bv;
                if (by < 2) V[(size_t)(rg + q) * 256 + cg] = f2bf(v);
                else        OA[(size_t)(rg + q) * 384 + (cg - 256)] = v;
            }
        }
    }
}

// =============== input conversion ===============
__global__ __launch_bounds__(256) void convq_k(const float* __restrict__ q, const float* __restrict__ qp,
                                               ushort_t* __restrict__ qb, ushort_t* __restrict__ qpb)
{
    const int i = blockIdx.x * 256 + threadIdx.x;
    const size_t e = (size_t)i * 4;
    const int row = i >> 6;
    ushort4 o1, o2;
    if (row < M_ROWS) {
        float4 a = ld4(q + e);
        float4 b = ld4(qp + e);
        o1 = make_ushort4(f2bf(a.x), f2bf(a.y), f2bf(a.z), f2bf(a.w));
        o2 = make_ushort4(f2bf(a.x + b.x), f2bf(a.y + b.y), f2bf(a.z + b.z), f2bf(a.w + b.w));
    } else {
        o1 = make_ushort4(0, 0, 0, 0);
        o2 = o1;
    }
    *reinterpret_cast<ushort4*>(qb + e)  = o1;
    *reinterpret_cast<ushort4*>(qpb + e) = o2;
}

// =============== combined weight transpose+convert (6 matrices) ===============
__global__ __launch_bounds__(256) void wtr_k(const float* W0, ushort_t* T0,
                                             const float* W1, ushort_t* T1,
                                             const float* W2, ushort_t* T2,
                                             const float* W3, ushort_t* T3,
                                             const float* W4, ushort_t* T4,
                                             const float* W5, ushort_t* T5)
{
    __shared__ float t[32][33];
    const float* W; ushort_t* T; int K, N;
    switch (blockIdx.z) {
        case 0: W = W0; T = T0; K = 256;  N = 256;  break;
        case 1: W = W1; T = T1; K = 256;  N = 256;  break;
        case 2: W = W2; T = T2; K = 256;  N = 128;  break;
        case 3: W = W3; T = T3; K = 256;  N = 256;  break;
        case 4: W = W4; T = T4; K = 256;  N = 1024; break;
        default:W = W5; T = T5; K = 1024; N = 256;  break;
    }
    const int kb = blockIdx.x * 32, nb = blockIdx.y * 32;
    if (kb >= K || nb >= N) return;
    const int x = threadIdx.x & 31, y0 = threadIdx.x >> 5;
    #pragma unroll
    for (int r = 0; r < 32; r += 8) t[y0 + r][x] = W[(size_t)(kb + y0 + r) * N + nb + x];
    __syncthreads();
    #pragma unroll
    for (int r = 0; r < 32; r += 8) T[(size_t)(nb + y0 + r) * K + kb + x] = f2bf(t[x][y0 + r]);
}

// =============== deformable sampling (softmax fused), 2 queries/block, 2 waves/query ===============
// Bijective XCD-chunk swizzle of blockIdx (m204): each XCD serves a contiguous query
// range -> V gathers concentrate in its private L2 (less cross-XCD duplication).
#define PIDX(i) ((i) + ((i) >> 4))
__global__ __launch_bounds__(256) void sample_k(const ushort_t* __restrict__ Vb,
                                                const float* __restrict__ OA,
                                                const float* __restrict__ REF,
                                                ushort_t* __restrict__ OUT)
{
    __shared__ int4  srowp[2][136];        // byte offsets (row*512)
    __shared__ f32x2 swtd[2][136 * 4];     // duplicated weight pairs
    __shared__ f32x2 pa[2][2][64];         // partial ch pair 0-1 per (query, wave, lane)
    __shared__ f32x2 pb[2][2][64];         // partial ch pair 2-3
    const int tid = threadIdx.x;
    const int ql = tid >> 7, idx = tid & 127;
    // bijective XCD swizzle: nwg = 11253 = 8*1406 + 5
    const int NWQ = 1406, RW = 5;
    const int bid = blockIdx.x;
    const int xcd = bid & 7, sub = bid >> 3;
    const int wg = (xcd < RW ? xcd * (NWQ + 1) : RW * (NWQ + 1) + (xcd - RW) * NWQ) + sub;
    const int bq = wg * 2 + ql;
    const int b  = (bq >= N_TOK) ? 1 : 0;

    {   // ---- phase 1: one (h,lvl,p) item per thread ----
        const int item = idx;
        const int h = item >> 4, lvl = (item >> 2) & 3, p = item & 3;
        const int HH[4] = {92, 46, 23, 12};
        const int ST[4] = {0, 8464, 10580, 11109};
        const int Hs = HH[lvl], Ws = Hs, st = ST[lvl];
        const float fW = (float)Ws, fH = (float)Hs;

        float logit = OA[(size_t)bq * 384 + 256 + item];
        float mx = logit;
        #pragma unroll
        for (int m = 8; m >= 1; m >>= 1) mx = fmaxf(mx, __shfl_xor(mx, m, 16));
        float e = expf(logit - mx);
        float ssum = e;
        #pragma unroll
        for (int m = 8; m >= 1; m >>= 1) ssum += __shfl_xor(ssum, m, 16);
        const float a = e / ssum;

        const float ox = OA[(size_t)bq * 384 + h * 32 + lvl * 8 + p * 2];
        const float oy = OA[(size_t)bq * 384 + h * 32 + lvl * 8 + p * 2 + 1];
        const float rx = REF[(size_t)bq * 8 + lvl * 2];
        const float ry = REF[(size_t)bq * 8 + lvl * 2 + 1];
        const float x = rx * fW + ox - 0.5f;
        const float y = ry * fH + oy - 0.5f;
        const float xf = floorf(x), yf = floorf(y);
        const float wx = x - xf, wy = y - yf;
        const int ix = (int)xf, iy = (int)yf;
        const int x0 = min(max(ix, 0), Ws - 1),     x1 = min(max(ix + 1, 0), Ws - 1);
        const int y0 = min(max(iy, 0), Hs - 1),     y1 = min(max(iy + 1, 0), Hs - 1);
        const float vx0 = (ix >= 0 && ix < Ws) ? 1.f : 0.f;
        const float vx1 = (ix + 1 >= 0 && ix + 1 < Ws) ? 1.f : 0.f;
        const float vy0 = (iy >= 0 && iy < Hs) ? 1.f : 0.f;
        const float vy1 = (iy + 1 >= 0 && iy + 1 < Hs) ? 1.f : 0.f;
        const int rbase = b * N_TOK + st;
        const int pi = PIDX(item);
        srowp[ql][pi] = make_int4((rbase + y0 * Ws + x0) << 9, (rbase + y0 * Ws + x1) << 9,
                                  (rbase + y1 * Ws + x0) << 9, (rbase + y1 * Ws + x1) << 9);
        const float w00 = a * (1.f - wx) * (1.f - wy) * vx0 * vy0;
        const float w01 = a * wx * (1.f - wy) * vx1 * vy0;
        const float w10 = a * (1.f - wx) * wy * vx0 * vy1;
        const float w11 = a * wx * wy * vx1 * vy1;
        swtd[ql][pi * 4 + 0] = (f32x2){w00, w00};
        swtd[ql][pi * 4 + 1] = (f32x2){w01, w01};
        swtd[ql][pi * 4 + 2] = (f32x2){w10, w10};
        swtd[ql][pi * 4 + 3] = (f32x2){w11, w11};
    }
    __syncthreads();

    // ---- phase 2: 2 waves per query, 8 s-samples each ----
    const int sw = idx >> 6, l = idx & 63;
    const int h2 = l >> 3, ln8 = l & 7;
    const int s0 = sw * 8;
    const uint32 cb2 = (uint32)((h2 * 32 + ln8 * 4) * 2);   // byte offset within 512B row
    const char* vb = (const char*)Vb;
    f32x2 acc0a = {0.f, 0.f}, acc0b = {0.f, 0.f};
    f32x2 acc1a = {0.f, 0.f}, acc1b = {0.f, 0.f};

    #pragma unroll
    for (int s = 0; s < 8; ++s) {
        const int pi = h2 * 17 + s0 + s;       // PIDX(h2*16 + s0 + s)
        const int4 ro = srowp[ql][pi];
        const u32x2 u0 = *reinterpret_cast<const u32x2*>(vb + ((uint32)ro.x + cb2));
        const u32x2 u1 = *reinterpret_cast<const u32x2*>(vb + ((uint32)ro.y + cb2));
        const u32x2 u2 = *reinterpret_cast<const u32x2*>(vb + ((uint32)ro.z + cb2));
        const u32x2 u3 = *reinterpret_cast<const u32x2*>(vb + ((uint32)ro.w + cb2));
        const f32x2 wp0 = swtd[ql][pi * 4 + 0];
        const f32x2 wp1 = swtd[ql][pi * 4 + 1];
        const f32x2 wp2 = swtd[ql][pi * 4 + 2];
        const f32x2 wp3 = swtd[ql][pi * 4 + 3];
        {
            f32x2 v0 = {__uint_as_float(u0.x << 16), __uint_as_float(u0.x & 0xffff0000u)};
            f32x2 v1 = {__uint_as_float(u0.y << 16), __uint_as_float(u0.y & 0xffff0000u)};
            asm("v_pk_fma_f32 %0, %1, %2, %0" : "+v"(acc0a) : "v"(wp0), "v"(v0));
            asm("v_pk_fma_f32 %0, %1, %2, %0" : "+v"(acc1a) : "v"(wp0), "v"(v1));
        }
        {
            f32x2 v0 = {__uint_as_float(u1.x << 16), __uint_as_float(u1.x & 0xffff0000u)};
            f32x2 v1 = {__uint_as_float(u1.y << 16), __uint_as_float(u1.y & 0xffff0000u)};
            asm("v_pk_fma_f32 %0, %1, %2, %0" : "+v"(acc0b) : "v"(wp1), "v"(v0));
            asm("v_pk_fma_f32 %0, %1, %2, %0" : "+v"(acc1b) : "v"(wp1), "v"(v1));
        }
        {
            f32x2 v0 = {__uint_as_float(u2.x << 16), __uint_as_float(u2.x & 0xffff0000u)};
            f32x2 v1 = {__uint_as_float(u2.y << 16), __uint_as_float(u2.y & 0xffff0000u)};
            asm("v_pk_fma_f32 %0, %1, %2, %0" : "+v"(acc0a) : "v"(wp2), "v"(v0));
            asm("v_pk_fma_f32 %0, %1, %2, %0" : "+v"(acc1a) : "v"(wp2), "v"(v1));
        }
        {
            f32x2 v0 = {__uint_as_float(u3.x << 16), __uint_as_float(u3.x & 0xffff0000u)};
            f32x2 v1 = {__uint_as_float(u3.y << 16), __uint_as_float(u3.y & 0xffff0000u)};
            asm("v_pk_fma_f32 %0, %1, %2, %0" : "+v"(acc0b) : "v"(wp3), "v"(v0));
            asm("v_pk_fma_f32 %0, %1, %2, %0" : "+v"(acc1b) : "v"(wp3), "v"(v1));
        }
    }
    f32x2 r01, r23;
    r01.x = acc0a.x + acc0b.x; r01.y = acc0a.y + acc0b.y;
    r23.x = acc1a.x + acc1b.x; r23.y = acc1a.y + acc1b.y;
    pa[ql][sw][l] = r01;
    pb[ql][sw][l] = r23;
    __syncthreads();

    // ---- reduce the 2 wave-partials, convert, store (wave 0 of each query) ----
    if (sw == 0) {
        f32x2 s01 = pa[ql][0][l], t01 = pa[ql][1][l];
        f32x2 s23 = pb[ql][0][l], t23 = pb[ql][1][l];
        s01.x += t01.x; s01.y += t01.y;
        s23.x += t23.x; s23.y += t23.y;
        u32x2 ov;
        ov.x = (uint32)f2bf(s01.x) | ((uint32)f2bf(s01.y) << 16);
        ov.y = (uint32)f2bf(s23.x) | ((uint32)f2bf(s23.y) << 16);
        *reinterpret_cast<u32x2*>((char*)OUT + (size_t)bq * 512 + cb2) = ov;
    }
}

// =============== residual + LayerNorm ===============
// X2 is f32 (IN2BF=0) or bf16 (IN2BF=1); optionally writes bf16 copy of output.
template<int WBF16, int IN2BF>
__global__ __launch_bounds__(256) void ln_k(const float* __restrict__ X1,
                                            const float* __restrict__ X2f,
                                            const ushort_t* __restrict__ X2b,
                                            const float* __restrict__ w, const float* __restrict__ b,
                                            float* __restrict__ outf, ushort_t* __restrict__ outb, int M)
{
    const int lane = threadIdx.x & 63;
    const int row  = blockIdx.x * 4 + (threadIdx.x >> 6);
    if (row >= M) return;
    const size_t base = (size_t)row * 256 + lane * 4;
    float4 v1 = ld4(X1 + base);
    float4 v2;
    if (IN2BF) {
        ushort4 u = *reinterpret_cast<const ushort4*>(X2b + base);
        v2 = make_float4(bf2f(u.x), bf2f(u.y), bf2f(u.z), bf2f(u.w));
    } else {
        v2 = ld4(X2f + base);
    }
    float x0 = v1.x + v2.x, x1 = v1.y + v2.y, x2 = v1.z + v2.z, x3 = v1.w + v2.w;
    float s = x0 + x1 + x2 + x3;
    #pragma unroll
    for (int m = 32; m >= 1; m >>= 1) s += __shfl_xor(s, m);
    const float mu = s * (1.f / 256.f);
    float d0 = x0 - mu, d1 = x1 - mu, d2 = x2 - mu, d3 = x3 - mu;
    float vs = d0 * d0 + d1 * d1 + d2 * d2 + d3 * d3;
    #pragma unroll
    for (int m = 32; m >= 1; m >>= 1) vs += __shfl_xor(vs, m);
    const float r = rsqrtf(vs * (1.f / 256.f) + 1e-5f);
    float4 wv = ld4(w + lane * 4), bv = ld4(b + lane * 4);
    float4 o;
    o.x = d0 * r * wv.x + bv.x;
    o.y = d1 * r * wv.y + bv.y;
    o.z = d2 * r * wv.z + bv.z;
    o.w = d3 * r * wv.w + bv.w;
    *reinterpret_cast<float4*>(outf + base) = o;
    if (WBF16) {
        *reinterpret_cast<ushort4*>(outb + base) =
            make_ushort4(f2bf(o.x), f2bf(o.y), f2bf(o.z), f2bf(o.w));
    }
}

extern "C" void kernel_launch(void* const* d_in, const int* in_sizes, int n_in,
                              void* d_out, int out_size, void* d_ws, size_t ws_size,
                              hipStream_t stream)
{
    const float* query   = (const float*)d_in[0];
    const float* qpos    = (const float*)d_in[1];
    const float* refp    = (const float*)d_in[6];
    const float* w_value = (const float*)d_in[7];
    const float* b_value = (const float*)d_in[8];
    const float* w_off   = (const float*)d_in[9];
    const float* b_off   = (const float*)d_in[10];
    const float* w_attn  = (const float*)d_in[11];
    const float* b_attn  = (const float*)d_in[12];
    const float* w_out   = (const float*)d_in[13];
    const float* b_out   = (const float*)d_in[14];
    const float* w_ffn1  = (const float*)d_in[15];
    const float* b_ffn1  = (const float*)d_in[16];
    const float* w_ffn2  = (const float*)d_in[17];
    const float* b_ffn2  = (const float*)d_in[18];
    const float* ln1w    = (const float*)d_in[19];
    const float* ln1b    = (const float*)d_in[20];
    const float* ln2w    = (const float*)d_in[21];
    const float* ln2b    = (const float*)d_in[22];

    // ---- workspace layout (~83 MB) ----
    char* p = (char*)d_ws;
    ushort_t* qb   = (ushort_t*)p;                       // A: 23MB: qb+qpb -> X (f32) after LN1
    ushort_t* qpb  = qb + (size_t)MP * 256;
    float*    X    = (float*)p;
    p += (size_t)MP * 256 * 4;
    ushort_t* Wt_v = (ushort_t*)p;  p += 256 * 256 * 2;  // Wt_v + Wt_oa contiguous = Wcat [640][256]
    ushort_t* Wt_oa= (ushort_t*)p;  p += 384 * 256 * 2;
    ushort_t* Wt_u = (ushort_t*)p;  p += 256 * 256 * 2;
    ushort_t* Wt_1 = (ushort_t*)p;  p += 1024 * 256 * 2;
    ushort_t* Wt_2 = (ushort_t*)p;  p += 256 * 1024 * 2;
    ushort_t* V    = (ushort_t*)p;                       // B: 11.5MB: V -> Xb -> Y2b
    ushort_t* Xb   = (ushort_t*)p;
    ushort_t* Y2b  = (ushort_t*)p;
    p += (size_t)MP * 256 * 2;
    float*    OA   = (float*)p;                          // C: 46.1MB: OA(34.6) -> O(23) -> Y1(46.1)
    float*    O    = (float*)p;
    ushort_t* Y1   = (ushort_t*)p;
    ushort_t* SAMP = (ushort_t*)(p + (size_t)MP * 384 * 4);   // C tail: 11.5MB, past OA
    p += (size_t)MP * 384 * 4 + (size_t)MP * 256 * 2;

    // ---- prep ----
    convq_k<<<MP / 4, 256, 0, stream>>>(query, qpos, qb, qpb);
    wtr_k<<<dim3(32, 32, 6), 256, 0, stream>>>(w_value, Wt_v,
                                               w_off,  Wt_oa,
                                               w_attn, Wt_oa + 256 * 256,
                                               w_out,  Wt_u,
                                               w_ffn1, Wt_1,
                                               w_ffn2, Wt_2);

    const int GM = MP / 128;   // 176
    // merged value + offsets/attn GEMM (880 blocks, n-fastest)
    vgemm_k<<<dim3(5, GM), 256, 0, stream>>>(qb, qpb, Wt_v, b_value, b_off, b_attn, V, OA);
    // sampling (softmax fused, XCD-swizzled)
    sample_k<<<dim3(M_ROWS / 2), 256, 0, stream>>>(V, OA, refp, SAMP);
    // out-projection -> O (f32), 128x64 tiles = 704 blocks
    mgemm64_k<256, 0, 0><<<dim3(4, GM), 256, 0, stream>>>(SAMP, Wt_u, b_out, O, nullptr, 256);
    // x = LN(query + O) -> X (f32) + Xb (bf16)
    ln_k<1, 0><<<dim3((M_ROWS + 3) / 4), 256, 0, stream>>>(query, O, nullptr, ln1w, ln1b, X, Xb, M_ROWS);
    // FFN1 full-M: Xb -> Y1, 128x128 tiles, n-fastest (1408 blocks)
    mgemm_k<256, 1, 1><<<dim3(8, GM), 256, 0, stream>>>(Xb, Wt_1, b_ffn1, nullptr, Y1, 1024);
    // FFN2: Y1 -> Y2b (bf16), 128x64 tiles = 704 blocks
    mgemm64_k<1024, 1, 0><<<dim3(4, GM), 256, 0, stream>>>(Y1, Wt_2, b_ffn2, nullptr, Y2b, 256);
    // final LN -> d_out
    ln_k<0, 1><<<dim3((M_ROWS + 3) / 4), 256, 0, stream>>>(X, nullptr, Y2b, ln2w, ln2b, (float*)d_out, nullptr, M_ROWS);
}

// Round 11
// 277.823 us; speedup vs baseline: 1.0633x; 1.0633x over previous
//
#include <hip/hip_runtime.h>
#include <math.h>

// ---- problem constants ----
#define N_TOK  11253
#define M_ROWS 22506
#define MP     22528          // M padded to multiple of 128
// levels: (H,W)=(92,92),(46,46),(23,23),(12,12); starts 0,8464,10580,11109

typedef __attribute__((ext_vector_type(8))) short bf16x8;
typedef __attribute__((ext_vector_type(4))) float f32x4;
typedef __attribute__((ext_vector_type(2))) float f32x2;
typedef __attribute__((ext_vector_type(2))) unsigned int u32x2;
typedef unsigned short ushort_t;
typedef unsigned int   uint32;

__device__ __forceinline__ float4 ld4(const float* p) { return *reinterpret_cast<const float4*>(p); }
__device__ __forceinline__ ushort_t f2bf(float f) {          // round-to-nearest-even
    uint32 u = __float_as_uint(f);
    u += 0x7fffu + ((u >> 16) & 1u);
    return (ushort_t)(u >> 16);
}
__device__ __forceinline__ float bf2f(ushort_t h) { return __uint_as_float(((uint32)h) << 16); }
__device__ __forceinline__ void gl_lds16(const void* g, void* l) {
    __builtin_amdgcn_global_load_lds(
        (const __attribute__((address_space(1))) unsigned int*)g,
        (__attribute__((address_space(3))) unsigned int*)l, 16, 0, 0);
}

// =============== bf16 MFMA GEMM: C = A @ Bt^T + bias (128x128 tile, m-fastest grid) ===============
// LDS swizzle: elem (r,k) at byte r*128 + (k*2 ^ ((r&7)<<4)); gl_lds dest linear,
// per-lane global source inverse-swizzled (rule 21).
template<int K, int OUT_BF16, int RELU>
__global__ __launch_bounds__(256) void mgemm_k(const ushort_t* __restrict__ A,
                                               const ushort_t* __restrict__ Bt,
                                               const float* __restrict__ bias,
                                               float* __restrict__ Cf,
                                               ushort_t* __restrict__ Cb,
                                               int Nout)
{
    __shared__ ushort_t As[128 * 64];   // 16KB
    __shared__ ushort_t Bs[128 * 64];   // 16KB
    const int tid = threadIdx.x;
    const int w = tid >> 6, l = tid & 63;
    const int wr = w >> 1, wc = w & 1;
    const int m0 = blockIdx.x * 128, n0 = blockIdx.y * 128;

    f32x4 acc[4][4];
    #pragma unroll
    for (int m = 0; m < 4; ++m)
        #pragma unroll
        for (int n = 0; n < 4; ++n)
            acc[m][n] = (f32x4){0.f, 0.f, 0.f, 0.f};

    const int srl  = l >> 3;
    const int skof = ((l & 7) ^ srl) << 3;
    const ushort_t* Agl = A  + (size_t)(m0 + srl) * K + skof;
    const ushort_t* Bgl = Bt + (size_t)(n0 + srl) * K + skof;

    const int fr = l & 15, fh = l >> 4;
    const int swz = (fr & 7) << 3;

    for (int k0 = 0; k0 < K; k0 += 64) {
        __syncthreads();
        #pragma unroll
        for (int j = 0; j < 4; ++j) {
            const int c = w + j * 4;
            gl_lds16(Agl + (size_t)(c * 8) * K + k0, &As[c * 512]);
            gl_lds16(Bgl + (size_t)(c * 8) * K + k0, &Bs[c * 512]);
        }
        __syncthreads();
        #pragma unroll
        for (int ks = 0; ks < 2; ++ks) {
            const int kus = (ks * 32 + fh * 8) ^ swz;
            bf16x8 af[4], bfv[4];
            #pragma unroll
            for (int m = 0; m < 4; ++m)
                af[m] = *reinterpret_cast<const bf16x8*>(&As[(wr * 64 + m * 16 + fr) * 64 + kus]);
            #pragma unroll
            for (int n = 0; n < 4; ++n)
                bfv[n] = *reinterpret_cast<const bf16x8*>(&Bs[(wc * 64 + n * 16 + fr) * 64 + kus]);
            #pragma unroll
            for (int m = 0; m < 4; ++m)
                #pragma unroll
                for (int n = 0; n < 4; ++n)
                    acc[m][n] = __builtin_amdgcn_mfma_f32_16x16x32_bf16(af[m], bfv[n], acc[m][n], 0, 0, 0);
        }
    }

    const int col0 = n0 + wc * 64;
    #pragma unroll
    for (int n = 0; n < 4; ++n) {
        const int cg = col0 + n * 16 + fr;
        const float bv = bias[cg];
        #pragma unroll
        for (int m = 0; m < 4; ++m) {
            const int rg = m0 + wr * 64 + m * 16 + fh * 4;
            #pragma unroll
            for (int q = 0; q < 4; ++q) {
                float v = acc[m][n][q] + bv;
                if (RELU) v = fmaxf(v, 0.f);
                const size_t o = (size_t)(rg + q) * Nout + cg;
                if (OUT_BF16) Cb[o] = f2bf(v);
                else          Cf[o] = v;
            }
        }
    }
}

// =============== fused GEMM (full 256-wide) + residual + LayerNorm, 32-row tile ===============
// Grid: MP/32 = 704 blocks (vs 352 at 64 rows: fixes the 1.4-blocks/CU latency limit of R7).
// 4 waves, each owns a 32x64 quadrant: acc[2][4]. LDS ~37KB.
// out = LN(RES + A@Bt^T + bias) * lw + lb -> outf (f32) [+ outb bf16]
template<int K, int WB16>
__global__ __launch_bounds__(256) void mgemm_ln32_k(const ushort_t* __restrict__ A,
                                                    const ushort_t* __restrict__ Bt,
                                                    const float* __restrict__ bias,
                                                    const float* __restrict__ RES,
                                                    const float* __restrict__ lw,
                                                    const float* __restrict__ lb,
                                                    float* __restrict__ outf,
                                                    ushort_t* __restrict__ outb)
{
    __shared__ ushort_t As[32 * 64];     // 4KB
    __shared__ ushort_t Bs[256 * 64];    // 32KB
    __shared__ float part[32][4][2];     // per-row per-wave {sum, sumsq}
    __shared__ float mv[32][2];          // per-row {mu, rstd}
    const int tid = threadIdx.x;
    const int wid = tid >> 6, l = tid & 63;
    const int m0 = blockIdx.x * 32;

    f32x4 acc[2][4];
    #pragma unroll
    for (int m = 0; m < 2; ++m)
        #pragma unroll
        for (int n = 0; n < 4; ++n)
            acc[m][n] = (f32x4){0.f, 0.f, 0.f, 0.f};

    const int srl  = l >> 3;
    const int skof = ((l & 7) ^ srl) << 3;
    const ushort_t* Agl = A  + (size_t)(m0 + srl) * K + skof;
    const ushort_t* Bgl = Bt + (size_t)srl * K + skof;

    const int fr = l & 15, fh = l >> 4;
    const int swz = (fr & 7) << 3;

    for (int k0 = 0; k0 < K; k0 += 64) {
        __syncthreads();
        // 36 chunks of 1KB: 0-3 = A rows 8c..8c+8; 4-35 = B rows 8(c-4)..8(c-4)+8
        #pragma unroll
        for (int j = 0; j < 9; ++j) {
            const int c = wid + j * 4;
            if (c < 4) gl_lds16(Agl + (size_t)(c * 8) * K + k0, &As[c * 512]);
            else       gl_lds16(Bgl + (size_t)((c - 4) * 8) * K + k0, &Bs[(c - 4) * 512]);
        }
        __syncthreads();
        #pragma unroll
        for (int ks = 0; ks < 2; ++ks) {
            const int kus = (ks * 32 + fh * 8) ^ swz;
            bf16x8 af[2], bfv[4];
            #pragma unroll
            for (int m = 0; m < 2; ++m)
                af[m] = *reinterpret_cast<const bf16x8*>(&As[(m * 16 + fr) * 64 + kus]);
            #pragma unroll
            for (int n = 0; n < 4; ++n)
                bfv[n] = *reinterpret_cast<const bf16x8*>(&Bs[(wid * 64 + n * 16 + fr) * 64 + kus]);
            #pragma unroll
            for (int m = 0; m < 2; ++m)
                #pragma unroll
                for (int n = 0; n < 4; ++n)
                    acc[m][n] = __builtin_amdgcn_mfma_f32_16x16x32_bf16(af[m], bfv[n], acc[m][n], 0, 0, 0);
        }
    }

    // ---- epilogue: add bias + residual, per-row LN ----
    const int colb = wid * 64;
    float psum[2][4], psq[2][4];
    #pragma unroll
    for (int m = 0; m < 2; ++m)
        #pragma unroll
        for (int q = 0; q < 4; ++q) { psum[m][q] = 0.f; psq[m][q] = 0.f; }

    #pragma unroll
    for (int n = 0; n < 4; ++n) {
        const int cg = colb + n * 16 + fr;
        const float bv = bias[cg];
        #pragma unroll
        for (int m = 0; m < 2; ++m) {
            const int rg = m0 + m * 16 + fh * 4;
            #pragma unroll
            for (int q = 0; q < 4; ++q) {
                const int row = rg + q;
                float rv = (row < M_ROWS) ? RES[(size_t)row * 256 + cg] : 0.f;
                float v = acc[m][n][q] + bv + rv;
                acc[m][n][q] = v;
                psum[m][q] += v;
                psq[m][q]  += v * v;
            }
        }
    }
    #pragma unroll
    for (int m = 0; m < 2; ++m)
        #pragma unroll
        for (int q = 0; q < 4; ++q) {
            float s = psum[m][q], ss = psq[m][q];
            #pragma unroll
            for (int mk = 8; mk >= 1; mk >>= 1) {
                s  += __shfl_xor(s,  mk, 16);
                ss += __shfl_xor(ss, mk, 16);
            }
            if (fr == 0) {
                const int row = m * 16 + fh * 4 + q;
                part[row][wid][0] = s;
                part[row][wid][1] = ss;
            }
        }
    __syncthreads();
    if (wid == 0 && l < 32) {
        float s = 0.f, ss = 0.f;
        #pragma unroll
        for (int j = 0; j < 4; ++j) { s += part[l][j][0]; ss += part[l][j][1]; }
        const float mu  = s * (1.f / 256.f);
        const float var = ss * (1.f / 256.f) - mu * mu;
        mv[l][0] = mu;
        mv[l][1] = rsqrtf(var + 1e-5f);
    }
    __syncthreads();
    #pragma unroll
    for (int m = 0; m < 2; ++m) {
        #pragma unroll
        for (int q = 0; q < 4; ++q) {
            const int rowt = m * 16 + fh * 4 + q;
            const int row  = m0 + rowt;
            const float mu = mv[rowt][0], rs = mv[rowt][1];
            if (row < M_ROWS) {
                #pragma unroll
                for (int n = 0; n < 4; ++n) {
                    const int cg = colb + n * 16 + fr;
                    const float o = (acc[m][n][q] - mu) * rs * lw[cg] + lb[cg];
                    outf[(size_t)row * 256 + cg] = o;
                    if (WB16) outb[(size_t)row * 256 + cg] = f2bf(o);
                }
            }
        }
    }
}

// =============== merged front GEMM: [V | OA] = [qb|qpb] @ [Wv|Woa]^T ===============
// blockIdx.y 0-1: A=qb, out V bf16 cols 0-255; y 2-4: A=qpb, out OA f32 cols 0-383
__global__ __launch_bounds__(256) void vgemm_k(const ushort_t* __restrict__ qb,
                                               const ushort_t* __restrict__ qpb,
                                               const ushort_t* __restrict__ Wcat,
                                               const float* __restrict__ b_value,
                                               const float* __restrict__ b_off,
                                               const float* __restrict__ b_attn,
                                               ushort_t* __restrict__ V,
                                               float* __restrict__ OA)
{
    const int K = 256;
    __shared__ ushort_t As[128 * 64];
    __shared__ ushort_t Bs[128 * 64];
    const int tid = threadIdx.x;
    const int w = tid >> 6, l = tid & 63;
    const int wr = w >> 1, wc = w & 1;
    const int by = blockIdx.y;
    const int m0 = blockIdx.x * 128, n0 = by * 128;
    const ushort_t* A = (by < 2) ? qb : qpb;

    f32x4 acc[4][4];
    #pragma unroll
    for (int m = 0; m < 4; ++m)
        #pragma unroll
        for (int n = 0; n < 4; ++n)
            acc[m][n] = (f32x4){0.f, 0.f, 0.f, 0.f};

    const int srl  = l >> 3;
    const int skof = ((l & 7) ^ srl) << 3;
    const ushort_t* Agl = A    + (size_t)(m0 + srl) * K + skof;
    const ushort_t* Bgl = Wcat + (size_t)(n0 + srl) * K + skof;

    const int fr = l & 15, fh = l >> 4;
    const int swz = (fr & 7) << 3;

    for (int k0 = 0; k0 < K; k0 += 64) {
        __syncthreads();
        #pragma unroll
        for (int j = 0; j < 4; ++j) {
            const int c = w + j * 4;
            gl_lds16(Agl + (size_t)(c * 8) * K + k0, &As[c * 512]);
            gl_lds16(Bgl + (size_t)(c * 8) * K + k0, &Bs[c * 512]);
        }
        __syncthreads();
        #pragma unroll
        for (int ks = 0; ks < 2; ++ks) {
            const int kus = (ks * 32 + fh * 8) ^ swz;
            bf16x8 af[4], bfv[4];
            #pragma unroll
            for (int m = 0; m < 4; ++m)
                af[m] = *reinterpret_cast<const bf16x8*>(&As[(wr * 64 + m * 16 + fr) * 64 + kus]);
            #pragma unroll
            for (int n = 0; n < 4; ++n)
                bfv[n] = *reinterpret_cast<const bf16x8*>(&Bs[(wc * 64 + n * 16 + fr) * 64 + kus]);
            #pragma unroll
            for (int m = 0; m < 4; ++m)
                #pragma unroll
                for (int n = 0; n < 4; ++n)
                    acc[m][n] = __builtin_amdgcn_mfma_f32_16x16x32_bf16(af[m], bfv[n], acc[m][n], 0, 0, 0);
        }
    }

    const int col0 = n0 + wc * 64;
    #pragma unroll
    for (int n = 0; n < 4; ++n) {
        const int cg = col0 + n * 16 + fr;
        float bv;
        if (by < 2)           bv = b_value[cg];
        else if (cg < 512)    bv = b_off[cg - 256];
        else                  bv = b_attn[cg - 512];
        #pragma unroll
        for (int m = 0; m < 4; ++m) {
            const int rg = m0 + wr * 64 + m * 16 + fh * 4;
            #pragma unroll
            for (int q = 0; q < 4; ++q) {
                const float v = acc[m][n][q] + bv;
                if (by < 2) V[(size_t)(rg + q) * 256 + cg] = f2bf(v);
                else        OA[(size_t)(rg + q) * 384 + (cg - 256)] = v;
            }
        }
    }
}

// =============== input conversion ===============
__global__ __launch_bounds__(256) void convq_k(const float* __restrict__ q, const float* __restrict__ qp,
                                               ushort_t* __restrict__ qb, ushort_t* __restrict__ qpb)
{
    const int i = blockIdx.x * 256 + threadIdx.x;
    const size_t e = (size_t)i * 4;
    const int row = i >> 6;
    ushort4 o1, o2;
    if (row < M_ROWS) {
        float4 a = ld4(q + e);
        float4 b = ld4(qp + e);
        o1 = make_ushort4(f2bf(a.x), f2bf(a.y), f2bf(a.z), f2bf(a.w));
        o2 = make_ushort4(f2bf(a.x + b.x), f2bf(a.y + b.y), f2bf(a.z + b.z), f2bf(a.w + b.w));
    } else {
        o1 = make_ushort4(0, 0, 0, 0);
        o2 = o1;
    }
    *reinterpret_cast<ushort4*>(qb + e)  = o1;
    *reinterpret_cast<ushort4*>(qpb + e) = o2;
}

// =============== combined weight transpose+convert (6 matrices) ===============
__global__ __launch_bounds__(256) void wtr_k(const float* W0, ushort_t* T0,
                                             const float* W1, ushort_t* T1,
                                             const float* W2, ushort_t* T2,
                                             const float* W3, ushort_t* T3,
                                             const float* W4, ushort_t* T4,
                                             const float* W5, ushort_t* T5)
{
    __shared__ float t[32][33];
    const float* W; ushort_t* T; int K, N;
    switch (blockIdx.z) {
        case 0: W = W0; T = T0; K = 256;  N = 256;  break;
        case 1: W = W1; T = T1; K = 256;  N = 256;  break;
        case 2: W = W2; T = T2; K = 256;  N = 128;  break;
        case 3: W = W3; T = T3; K = 256;  N = 256;  break;
        case 4: W = W4; T = T4; K = 256;  N = 1024; break;
        default:W = W5; T = T5; K = 1024; N = 256;  break;
    }
    const int kb = blockIdx.x * 32, nb = blockIdx.y * 32;
    if (kb >= K || nb >= N) return;
    const int x = threadIdx.x & 31, y0 = threadIdx.x >> 5;
    #pragma unroll
    for (int r = 0; r < 32; r += 8) t[y0 + r][x] = W[(size_t)(kb + y0 + r) * N + nb + x];
    __syncthreads();
    #pragma unroll
    for (int r = 0; r < 32; r += 8) T[(size_t)(nb + y0 + r) * K + kb + x] = f2bf(t[x][y0 + r]);
}

// =============== deformable sampling (softmax fused), 2 queries/block, 2 waves/query ===============
// Bijective XCD-chunk swizzle of blockIdx (m204) for V-gather L2 locality.
#define PIDX(i) ((i) + ((i) >> 4))
__global__ __launch_bounds__(256) void sample_k(const ushort_t* __restrict__ Vb,
                                                const float* __restrict__ OA,
                                                const float* __restrict__ REF,
                                                ushort_t* __restrict__ OUT)
{
    __shared__ int4  srowp[2][136];        // byte offsets (row*512)
    __shared__ f32x2 swtd[2][136 * 4];     // duplicated weight pairs
    __shared__ f32x2 pa[2][2][64];         // partial ch pair 0-1 per (query, wave, lane)
    __shared__ f32x2 pb[2][2][64];         // partial ch pair 2-3
    const int tid = threadIdx.x;
    const int ql = tid >> 7, idx = tid & 127;
    // bijective XCD swizzle: nwg = 11253 = 8*1406 + 5
    const int NWQ = 1406, RW = 5;
    const int bid = blockIdx.x;
    const int xcd = bid & 7, sub = bid >> 3;
    const int wg = (xcd < RW ? xcd * (NWQ + 1) : RW * (NWQ + 1) + (xcd - RW) * NWQ) + sub;
    const int bq = wg * 2 + ql;
    const int b  = (bq >= N_TOK) ? 1 : 0;

    {   // ---- phase 1: one (h,lvl,p) item per thread ----
        const int item = idx;
        const int h = item >> 4, lvl = (item >> 2) & 3, p = item & 3;
        const int HH[4] = {92, 46, 23, 12};
        const int ST[4] = {0, 8464, 10580, 11109};
        const int Hs = HH[lvl], Ws = Hs, st = ST[lvl];
        const float fW = (float)Ws, fH = (float)Hs;

        float logit = OA[(size_t)bq * 384 + 256 + item];
        float mx = logit;
        #pragma unroll
        for (int m = 8; m >= 1; m >>= 1) mx = fmaxf(mx, __shfl_xor(mx, m, 16));
        float e = expf(logit - mx);
        float ssum = e;
        #pragma unroll
        for (int m = 8; m >= 1; m >>= 1) ssum += __shfl_xor(ssum, m, 16);
        const float a = e / ssum;

        const float ox = OA[(size_t)bq * 384 + h * 32 + lvl * 8 + p * 2];
        const float oy = OA[(size_t)bq * 384 + h * 32 + lvl * 8 + p * 2 + 1];
        const float rx = REF[(size_t)bq * 8 + lvl * 2];
        const float ry = REF[(size_t)bq * 8 + lvl * 2 + 1];
        const float x = rx * fW + ox - 0.5f;
        const float y = ry * fH + oy - 0.5f;
        const float xf = floorf(x), yf = floorf(y);
        const float wx = x - xf, wy = y - yf;
        const int ix = (int)xf, iy = (int)yf;
        const int x0 = min(max(ix, 0), Ws - 1),     x1 = min(max(ix + 1, 0), Ws - 1);
        const int y0 = min(max(iy, 0), Hs - 1),     y1 = min(max(iy + 1, 0), Hs - 1);
        const float vx0 = (ix >= 0 && ix < Ws) ? 1.f : 0.f;
        const float vx1 = (ix + 1 >= 0 && ix + 1 < Ws) ? 1.f : 0.f;
        const float vy0 = (iy >= 0 && iy < Hs) ? 1.f : 0.f;
        const float vy1 = (iy + 1 >= 0 && iy + 1 < Hs) ? 1.f : 0.f;
        const int rbase = b * N_TOK + st;
        const int pi = PIDX(item);
        srowp[ql][pi] = make_int4((rbase + y0 * Ws + x0) << 9, (rbase + y0 * Ws + x1) << 9,
                                  (rbase + y1 * Ws + x0) << 9, (rbase + y1 * Ws + x1) << 9);
        const float w00 = a * (1.f - wx) * (1.f - wy) * vx0 * vy0;
        const float w01 = a * wx * (1.f - wy) * vx1 * vy0;
        const float w10 = a * (1.f - wx) * wy * vx0 * vy1;
        const float w11 = a * wx * wy * vx1 * vy1;
        swtd[ql][pi * 4 + 0] = (f32x2){w00, w00};
        swtd[ql][pi * 4 + 1] = (f32x2){w01, w01};
        swtd[ql][pi * 4 + 2] = (f32x2){w10, w10};
        swtd[ql][pi * 4 + 3] = (f32x2){w11, w11};
    }
    __syncthreads();

    // ---- phase 2: 2 waves per query, 8 s-samples each ----
    const int sw = idx >> 6, l = idx & 63;
    const int h2 = l >> 3, ln8 = l & 7;
    const int s0 = sw * 8;
    const uint32 cb2 = (uint32)((h2 * 32 + ln8 * 4) * 2);   // byte offset within 512B row
    const char* vb = (const char*)Vb;
    f32x2 acc0a = {0.f, 0.f}, acc0b = {0.f, 0.f};
    f32x2 acc1a = {0.f, 0.f}, acc1b = {0.f, 0.f};

    #pragma unroll
    for (int s = 0; s < 8; ++s) {
        const int pi = h2 * 17 + s0 + s;       // PIDX(h2*16 + s0 + s)
        const int4 ro = srowp[ql][pi];
        const u32x2 u0 = *reinterpret_cast<const u32x2*>(vb + ((uint32)ro.x + cb2));
        const u32x2 u1 = *reinterpret_cast<const u32x2*>(vb + ((uint32)ro.y + cb2));
        const u32x2 u2 = *reinterpret_cast<const u32x2*>(vb + ((uint32)ro.z + cb2));
        const u32x2 u3 = *reinterpret_cast<const u32x2*>(vb + ((uint32)ro.w + cb2));
        const f32x2 wp0 = swtd[ql][pi * 4 + 0];
        const f32x2 wp1 = swtd[ql][pi * 4 + 1];
        const f32x2 wp2 = swtd[ql][pi * 4 + 2];
        const f32x2 wp3 = swtd[ql][pi * 4 + 3];
        {
            f32x2 v0 = {__uint_as_float(u0.x << 16), __uint_as_float(u0.x & 0xffff0000u)};
            f32x2 v1 = {__uint_as_float(u0.y << 16), __uint_as_float(u0.y & 0xffff0000u)};
            asm("v_pk_fma_f32 %0, %1, %2, %0" : "+v"(acc0a) : "v"(wp0), "v"(v0));
            asm("v_pk_fma_f32 %0, %1, %2, %0" : "+v"(acc1a) : "v"(wp0), "v"(v1));
        }
        {
            f32x2 v0 = {__uint_as_float(u1.x << 16), __uint_as_float(u1.x & 0xffff0000u)};
            f32x2 v1 = {__uint_as_float(u1.y << 16), __uint_as_float(u1.y & 0xffff0000u)};
            asm("v_pk_fma_f32 %0, %1, %2, %0" : "+v"(acc0b) : "v"(wp1), "v"(v0));
            asm("v_pk_fma_f32 %0, %1, %2, %0" : "+v"(acc1b) : "v"(wp1), "v"(v1));
        }
        {
            f32x2 v0 = {__uint_as_float(u2.x << 16), __uint_as_float(u2.x & 0xffff0000u)};
            f32x2 v1 = {__uint_as_float(u2.y << 16), __uint_as_float(u2.y & 0xffff0000u)};
            asm("v_pk_fma_f32 %0, %1, %2, %0" : "+v"(acc0a) : "v"(wp2), "v"(v0));
            asm("v_pk_fma_f32 %0, %1, %2, %0" : "+v"(acc1a) : "v"(wp2), "v"(v1));
        }
        {
            f32x2 v0 = {__uint_as_float(u3.x << 16), __uint_as_float(u3.x & 0xffff0000u)};
            f32x2 v1 = {__uint_as_float(u3.y << 16), __uint_as_float(u3.y & 0xffff0000u)};
            asm("v_pk_fma_f32 %0, %1, %2, %0" : "+v"(acc0b) : "v"(wp3), "v"(v0));
            asm("v_pk_fma_f32 %0, %1, %2, %0" : "+v"(acc1b) : "v"(wp3), "v"(v1));
        }
    }
    f32x2 r01, r23;
    r01.x = acc0a.x + acc0b.x; r01.y = acc0a.y + acc0b.y;
    r23.x = acc1a.x + acc1b.x; r23.y = acc1a.y + acc1b.y;
    pa[ql][sw][l] = r01;
    pb[ql][sw][l] = r23;
    __syncthreads();

    // ---- reduce the 2 wave-partials, convert, store (wave 0 of each query) ----
    if (sw == 0) {
        f32x2 s01 = pa[ql][0][l], t01 = pa[ql][1][l];
        f32x2 s23 = pb[ql][0][l], t23 = pb[ql][1][l];
        s01.x += t01.x; s01.y += t01.y;
        s23.x += t23.x; s23.y += t23.y;
        u32x2 ov;
        ov.x = (uint32)f2bf(s01.x) | ((uint32)f2bf(s01.y) << 16);
        ov.y = (uint32)f2bf(s23.x) | ((uint32)f2bf(s23.y) << 16);
        *reinterpret_cast<u32x2*>((char*)OUT + (size_t)bq * 512 + cb2) = ov;
    }
}

extern "C" void kernel_launch(void* const* d_in, const int* in_sizes, int n_in,
                              void* d_out, int out_size, void* d_ws, size_t ws_size,
                              hipStream_t stream)
{
    const float* query   = (const float*)d_in[0];
    const float* qpos    = (const float*)d_in[1];
    const float* refp    = (const float*)d_in[6];
    const float* w_value = (const float*)d_in[7];
    const float* b_value = (const float*)d_in[8];
    const float* w_off   = (const float*)d_in[9];
    const float* b_off   = (const float*)d_in[10];
    const float* w_attn  = (const float*)d_in[11];
    const float* b_attn  = (const float*)d_in[12];
    const float* w_out   = (const float*)d_in[13];
    const float* b_out   = (const float*)d_in[14];
    const float* w_ffn1  = (const float*)d_in[15];
    const float* b_ffn1  = (const float*)d_in[16];
    const float* w_ffn2  = (const float*)d_in[17];
    const float* b_ffn2  = (const float*)d_in[18];
    const float* ln1w    = (const float*)d_in[19];
    const float* ln1b    = (const float*)d_in[20];
    const float* ln2w    = (const float*)d_in[21];
    const float* ln2b    = (const float*)d_in[22];

    // ---- workspace layout (~83 MB), same proven overlay as R7 ----
    char* p = (char*)d_ws;
    ushort_t* qb   = (ushort_t*)p;                       // A: 23MB: qb+qpb -> X (f32) after LN1
    ushort_t* qpb  = qb + (size_t)MP * 256;
    float*    X    = (float*)p;
    p += (size_t)MP * 256 * 4;
    ushort_t* Wt_v = (ushort_t*)p;  p += 256 * 256 * 2;  // Wt_v + Wt_oa contiguous = Wcat [640][256]
    ushort_t* Wt_oa= (ushort_t*)p;  p += 384 * 256 * 2;
    ushort_t* Wt_u = (ushort_t*)p;  p += 256 * 256 * 2;
    ushort_t* Wt_1 = (ushort_t*)p;  p += 1024 * 256 * 2;
    ushort_t* Wt_2 = (ushort_t*)p;  p += 256 * 1024 * 2;
    ushort_t* V    = (ushort_t*)p;                       // B: 11.5MB: V -> Xb after LN1
    ushort_t* Xb   = (ushort_t*)p;
    p += (size_t)MP * 256 * 2;
    float*    OA   = (float*)p;                          // C: OA(34.6MB) + SAMP(11.5MB) -> Y1(46.1MB)
    ushort_t* Y1   = (ushort_t*)p;
    ushort_t* SAMP = (ushort_t*)(p + (size_t)MP * 384 * 4);
    p += (size_t)MP * 384 * 4 + (size_t)MP * 256 * 2;

    // ---- prep ----
    convq_k<<<MP / 4, 256, 0, stream>>>(query, qpos, qb, qpb);
    wtr_k<<<dim3(32, 32, 6), 256, 0, stream>>>(w_value, Wt_v,
                                               w_off,  Wt_oa,
                                               w_attn, Wt_oa + 256 * 256,
                                               w_out,  Wt_u,
                                               w_ffn1, Wt_1,
                                               w_ffn2, Wt_2);

    const int GM = MP / 128;   // 176
    // merged value + offsets/attn GEMM (880 blocks, m-fastest as in the 279us champion)
    vgemm_k<<<dim3(GM, 5), 256, 0, stream>>>(qb, qpb, Wt_v, b_value, b_off, b_attn, V, OA);
    // sampling (softmax fused, XCD-swizzled)
    sample_k<<<dim3(M_ROWS / 2), 256, 0, stream>>>(V, OA, refp, SAMP);
    // out-projection + residual(query) + LN1 -> X (f32) + Xb (bf16), 704 blocks
    mgemm_ln32_k<256, 1><<<dim3(MP / 32), 256, 0, stream>>>(SAMP, Wt_u, b_out, query, ln1w, ln1b, X, Xb);
    // FFN1 full-M: Xb -> Y1 (overlays dead OA+SAMP), 1408 blocks
    mgemm_k<256, 1, 1><<<dim3(GM, 8), 256, 0, stream>>>(Xb, Wt_1, b_ffn1, nullptr, Y1, 1024);
    // FFN2 + residual(X) + LN2 -> d_out, 704 blocks
    mgemm_ln32_k<1024, 0><<<dim3(MP / 32), 256, 0, stream>>>(Y1, Wt_2, b_ffn2, X, ln2w, ln2b, (float*)d_out, nullptr);
}